// Round 1
// baseline (256.909 us; speedup 1.0000x reference)
//
#include <hip/hip_runtime.h>
#include <hip/hip_bf16.h>

// Problem constants (fixed by the reference)
#define B_DIM   16384
#define IN_DIM  512
#define H_DIM   512
#define K_DIM   1024          // IN + H concatenated
#define N4H     2048          // 4*H
#define BH      (B_DIM * H_DIM)

typedef __attribute__((ext_vector_type(8))) short  short8;   // 8 bf16 = one MFMA operand
typedef __attribute__((ext_vector_type(4))) short  short4v;  // 4 bf16 = 8B LDS write
typedef __attribute__((ext_vector_type(4))) float  f32x4;    // MFMA accumulator

__device__ inline void async_load16(const void* g, void* l) {
    __builtin_amdgcn_global_load_lds(
        (const __attribute__((address_space(1))) void*)g,
        (__attribute__((address_space(3)))       void*)l, 16, 0, 0);
}

__device__ inline short bf16bits(float f) {
    __hip_bfloat16 b = __float2bfloat16(f);
    return *reinterpret_cast<short*>(&b);
}

__device__ inline float sigmoidf_(float v) {
    return 1.0f / (1.0f + __expf(-v));
}
__device__ inline float tanhf_(float v) {
    v = fminf(fmaxf(v, -30.f), 30.f);
    float e = __expf(2.f * v);
    return (e - 1.f) / (e + 1.f);
}

// ---------------------------------------------------------------------------
// Prep: Wt[row][k] bf16, row permuted as nb*128 + gate*32 + col so each GEMM
// block reads 128 contiguous rows. k = 0..511 from Wx, 512..1023 from Wh.
// Also bias_p[row] = bx[n]+bh[n] with the same row permutation.
// ---------------------------------------------------------------------------
__global__ __launch_bounds__(256) void prep_weights(
    const float* __restrict__ Wx, const float* __restrict__ Wh,
    const float* __restrict__ bx, const float* __restrict__ bh,
    __hip_bfloat16* __restrict__ Wt, float* __restrict__ bias_p) {
    __shared__ __hip_bfloat16 tile[32][33];   // +1 pad breaks bank conflicts
    const int bid = blockIdx.x;               // 2048 blocks
    const int bk  = bid & 31;                 // k-tile (32 of them)
    const int bn  = bid >> 5;                 // n-tile (64 of them, 32 cols each)
    const int t   = threadIdx.x;
    const int kb  = bk * 32, nb = bn * 32;

    // read 32x32 fp32 tile, coalesced along n
#pragma unroll
    for (int r = 0; r < 4; ++r) {
        int k_loc = r * 8 + (t >> 5);
        int n_loc = t & 31;
        int kg = kb + k_loc;
        float v = (kg < IN_DIM) ? Wx[(size_t)kg * N4H + nb + n_loc]
                                : Wh[(size_t)(kg - IN_DIM) * N4H + nb + n_loc];
        tile[k_loc][n_loc] = __float2bfloat16(v);
    }
    __syncthreads();

    // write transposed: row = permuted n, 32 contiguous k (64B per row)
    {
        int n_loc = t >> 3;
        int k_loc = (t & 7) * 4;
        int ng = nb + n_loc;                  // 0..2047
        int g  = ng >> 9;                     // gate
        int c  = ng & 511;                    // h-col
        int row_out = (c >> 5) * 128 + g * 32 + (c & 31);
        short4v v4;
        v4.x = *reinterpret_cast<short*>(&tile[k_loc + 0][n_loc]);
        v4.y = *reinterpret_cast<short*>(&tile[k_loc + 1][n_loc]);
        v4.z = *reinterpret_cast<short*>(&tile[k_loc + 2][n_loc]);
        v4.w = *reinterpret_cast<short*>(&tile[k_loc + 3][n_loc]);
        *(short4v*)&Wt[(size_t)row_out * K_DIM + kb + k_loc] = v4;
    }

    // bias (8 blocks cover 2048 entries)
    if (bid < 8) {
        int ng = bid * 256 + t;
        int g  = ng >> 9;
        int c  = ng & 511;
        int ro = (c >> 5) * 128 + g * 32 + (c & 31);
        bias_p[ro] = bx[ng] + bh[ng];
    }
}

// ---------------------------------------------------------------------------
// Main fused kernel: GEMM (M=16384, N_eff=128/block, K=1024) + LSTM epilogue.
// Block tile: 128 rows x (4 gates x 32 h-cols). 4 waves, each 32 rows x all
// 128 eff-cols -> every lane holds i,f,g,o for its (row, h-col) pairs.
// ---------------------------------------------------------------------------
__global__ __launch_bounds__(256, 3) void lstm_gemm(
    const float* __restrict__ x, const float* __restrict__ h,
    const float* __restrict__ c_in,
    const __hip_bfloat16* __restrict__ Wt, const float* __restrict__ bias_p,
    float* __restrict__ out) {
    __shared__ __hip_bfloat16 lds_a[128 * 32];   // [m][k] 8KB
    __shared__ __hip_bfloat16 lds_b[128 * 32];   // [n][k] 8KB

    const int tid   = threadIdx.x;
    const int bn    = blockIdx.x & 15;   // h-col block (16)
    const int bm    = blockIdx.x >> 4;   // m block (128)
    const int w     = tid >> 6;
    const int lane  = tid & 63;
    const int col16 = lane & 15;
    const int quad  = lane >> 4;

    f32x4 acc[2][8];
#pragma unroll
    for (int mi = 0; mi < 2; ++mi)
#pragma unroll
        for (int ni = 0; ni < 8; ++ni)
            acc[mi][ni] = (f32x4){0.f, 0.f, 0.f, 0.f};

    const __hip_bfloat16* wt_base = Wt + (size_t)(bn * 128) * K_DIM;

    // B-tile async staging geometry (constant across K loop)
    const int chunk0 = w * 2;                        // two 1KB chunks per wave
    const int e0     = chunk0 * 512 + lane * 8;      // element index in tile
    const int bn_loc0 = e0 >> 5, bk_off0 = e0 & 31;
    const int e1     = (chunk0 + 1) * 512 + lane * 8;
    const int bn_loc1 = e1 >> 5, bk_off1 = e1 & 31;

    for (int kt = 0; kt < 32; ++kt) {
        const int kb = kt * 32;
        const float* aptr;
        int koff;
        if (kb < IN_DIM) { aptr = x; koff = kb; }
        else             { aptr = h; koff = kb - IN_DIM; }

        // ---- B: global_load_lds (bf16, 16B/lane) ----
        async_load16(wt_base + (size_t)bn_loc0 * K_DIM + kb + bk_off0,
                     (void*)(lds_b + chunk0 * 512));
        async_load16(wt_base + (size_t)bn_loc1 * K_DIM + kb + bk_off1,
                     (void*)(lds_b + (chunk0 + 1) * 512));

        // ---- A: fp32 float4 loads -> bf16 -> LDS ----
        float4 av[4];
#pragma unroll
        for (int j = 0; j < 4; ++j) {
            int cch = j * 256 + tid;                 // 0..1023 float4 chunks
            int row = cch >> 3;
            int kq  = (cch & 7) * 4;
            av[j] = *(const float4*)(aptr + (size_t)(bm * 128 + row) * IN_DIM
                                     + koff + kq);
        }
#pragma unroll
        for (int j = 0; j < 4; ++j) {
            int cch = j * 256 + tid;
            int row = cch >> 3;
            int kq  = (cch & 7) * 4;
            short4v sv;
            sv.x = bf16bits(av[j].x);
            sv.y = bf16bits(av[j].y);
            sv.z = bf16bits(av[j].z);
            sv.w = bf16bits(av[j].w);
            *(short4v*)&lds_a[row * 32 + kq] = sv;
        }
        __syncthreads();

        // ---- fragments + MFMA ----
        short8 afr[2], bfr[8];
#pragma unroll
        for (int mi = 0; mi < 2; ++mi)
            afr[mi] = *(const short8*)&lds_a[(w * 32 + mi * 16 + col16) * 32 + quad * 8];
#pragma unroll
        for (int ni = 0; ni < 8; ++ni)
            bfr[ni] = *(const short8*)&lds_b[(ni * 16 + col16) * 32 + quad * 8];
#pragma unroll
        for (int mi = 0; mi < 2; ++mi)
#pragma unroll
            for (int ni = 0; ni < 8; ++ni)
                acc[mi][ni] = __builtin_amdgcn_mfma_f32_16x16x32_bf16(
                    afr[mi], bfr[ni], acc[mi][ni], 0, 0, 0);
        __syncthreads();
    }

    // ---- fused LSTM epilogue ----
    float bias_v[4][2];
#pragma unroll
    for (int g = 0; g < 4; ++g)
#pragma unroll
        for (int h2 = 0; h2 < 2; ++h2)
            bias_v[g][h2] = bias_p[bn * 128 + g * 32 + h2 * 16 + col16];

#pragma unroll
    for (int mi = 0; mi < 2; ++mi) {
#pragma unroll
        for (int reg = 0; reg < 4; ++reg) {
            const int m_g = bm * 128 + w * 32 + mi * 16 + quad * 4 + reg;
#pragma unroll
            for (int h2 = 0; h2 < 2; ++h2) {
                const int hc_g = bn * 32 + h2 * 16 + col16;
                float gi = acc[mi][0 + h2][reg] + bias_v[0][h2];
                float gf = acc[mi][2 + h2][reg] + bias_v[1][h2];
                float gg = acc[mi][4 + h2][reg] + bias_v[2][h2];
                float go = acc[mi][6 + h2][reg] + bias_v[3][h2];
                float iv = sigmoidf_(gi);
                float fv = sigmoidf_(gf);
                float gv = tanhf_(gg);
                float ov = sigmoidf_(go);
                float co = c_in[(size_t)m_g * H_DIM + hc_g];
                float cn = fv * co + iv * gv;
                float hn = ov * tanhf_(cn);
                out[(size_t)m_g * H_DIM + hc_g]      = hn;   // h_new
                out[BH + (size_t)m_g * H_DIM + hc_g] = cn;   // c_new
            }
        }
    }
}

extern "C" void kernel_launch(void* const* d_in, const int* in_sizes, int n_in,
                              void* d_out, int out_size, void* d_ws, size_t ws_size,
                              hipStream_t stream) {
    const float* x  = (const float*)d_in[0];
    const float* h  = (const float*)d_in[1];
    const float* c  = (const float*)d_in[2];
    const float* Wx = (const float*)d_in[3];
    const float* Wh = (const float*)d_in[4];
    const float* bx = (const float*)d_in[5];
    const float* bh = (const float*)d_in[6];

    __hip_bfloat16* Wt = (__hip_bfloat16*)d_ws;                       // 4 MB
    float* bias_p = (float*)((char*)d_ws + (size_t)N4H * K_DIM * 2);  // 8 KB

    prep_weights<<<2048, 256, 0, stream>>>(Wx, Wh, bx, bh, Wt, bias_p);
    lstm_gemm<<<2048, 256, 0, stream>>>(x, h, c, Wt, bias_p, (float*)d_out);
}

// Round 2
// 250.760 us; speedup vs baseline: 1.0245x; 1.0245x over previous
//
#include <hip/hip_runtime.h>
#include <hip/hip_bf16.h>

// Problem constants (fixed by the reference)
#define B_DIM   16384
#define IN_DIM  512
#define H_DIM   512
#define K_DIM   1024          // IN + H concatenated
#define N4H     2048          // 4*H
#define BH      (B_DIM * H_DIM)

typedef __attribute__((ext_vector_type(8))) short  short8;   // 8 bf16 = one MFMA operand
typedef __attribute__((ext_vector_type(4))) short  short4v;  // 4 bf16 = 8B LDS/global write
typedef __attribute__((ext_vector_type(4))) float  f32x4;    // MFMA accumulator

__device__ inline void async_load16(const void* g, void* l) {
    __builtin_amdgcn_global_load_lds(
        (const __attribute__((address_space(1))) void*)g,
        (__attribute__((address_space(3)))       void*)l, 16, 0, 0);
}

__device__ inline short bf16bits(float f) {
    __hip_bfloat16 b = __float2bfloat16(f);
    return *reinterpret_cast<short*>(&b);
}

__device__ inline float sigmoidf_(float v) {
    return 1.0f / (1.0f + __expf(-v));
}
__device__ inline float tanhf_(float v) {
    v = fminf(fmaxf(v, -30.f), 30.f);
    float e = __expf(2.f * v);
    return (e - 1.f) / (e + 1.f);
}

// ---------------------------------------------------------------------------
// Combined prep:
//   blocks [0,2048):   Wt[row][k] bf16, row permuted nb*128 + gate*32 + col
//                      (k 0..511 from Wx, 512..1023 from Wh) + bias fold
//   blocks [2048,4096): Axh[m][k] bf16 = x[m]||h[m]  (row-fused, GEMM-ready)
// ---------------------------------------------------------------------------
__global__ __launch_bounds__(256) void prep_all(
    const float* __restrict__ Wx, const float* __restrict__ Wh,
    const float* __restrict__ bx, const float* __restrict__ bh,
    const float* __restrict__ x,  const float* __restrict__ h,
    __hip_bfloat16* __restrict__ Wt, __hip_bfloat16* __restrict__ Axh,
    float* __restrict__ bias_p) {
    const int bid = blockIdx.x;
    const int t   = threadIdx.x;

    if (bid < 2048) {
        // ---- weight transpose+convert (same as validated R1 kernel) ----
        __shared__ __hip_bfloat16 tile[32][33];
        const int bk = bid & 31;
        const int bn = bid >> 5;
        const int kb = bk * 32, nb = bn * 32;
#pragma unroll
        for (int r = 0; r < 4; ++r) {
            int k_loc = r * 8 + (t >> 5);
            int n_loc = t & 31;
            int kg = kb + k_loc;
            float v = (kg < IN_DIM) ? Wx[(size_t)kg * N4H + nb + n_loc]
                                    : Wh[(size_t)(kg - IN_DIM) * N4H + nb + n_loc];
            tile[k_loc][n_loc] = __float2bfloat16(v);
        }
        __syncthreads();
        {
            int n_loc = t >> 3;
            int k_loc = (t & 7) * 4;
            int ng = nb + n_loc;
            int g  = ng >> 9;
            int c  = ng & 511;
            int row_out = (c >> 5) * 128 + g * 32 + (c & 31);
            short4v v4;
            v4.x = *reinterpret_cast<short*>(&tile[k_loc + 0][n_loc]);
            v4.y = *reinterpret_cast<short*>(&tile[k_loc + 1][n_loc]);
            v4.z = *reinterpret_cast<short*>(&tile[k_loc + 2][n_loc]);
            v4.w = *reinterpret_cast<short*>(&tile[k_loc + 3][n_loc]);
            *(short4v*)&Wt[(size_t)row_out * K_DIM + kb + k_loc] = v4;
        }
        if (bid < 8) {
            int ng = bid * 256 + t;
            int g  = ng >> 9;
            int c  = ng & 511;
            int ro = (c >> 5) * 128 + g * 32 + (c & 31);
            bias_p[ro] = bx[ng] + bh[ng];
        }
    } else {
        // ---- x||h -> bf16 Axh. kq = t is wave-uniform in source select ----
        const int ab = bid - 2048;              // 0..2047, 8 rows each
        const int kq = t;                       // float4 index within row
        const float* src = (kq < 128) ? (x + kq * 4)
                                      : (h + (size_t)(kq - 128) * 4);
#pragma unroll
        for (int j = 0; j < 8; ++j) {
            int m = ab * 8 + j;
            float4 v = *(const float4*)(src + (size_t)m * 512);
            short4v sv;
            sv.x = bf16bits(v.x);
            sv.y = bf16bits(v.y);
            sv.z = bf16bits(v.z);
            sv.w = bf16bits(v.w);
            *(short4v*)&Axh[(size_t)m * K_DIM + kq * 4] = sv;
        }
    }
}

// ---------------------------------------------------------------------------
// Main fused kernel (pure bf16, m97 structure):
//   A and B both staged via global_load_lds width=16.
//   LDS slot swizzle: slot(r,q) = r*4 + ((q + (r>>1)) & 3)  -> each 8-lane
//   ds_read_b128 phase group covers all 8 bank-quads (conflict-free).
//   XCD swizzle: 16 bn-blocks sharing a bm run on one XCD -> A-tile L2 reuse.
// ---------------------------------------------------------------------------
__global__ __launch_bounds__(256, 3) void lstm_gemm(
    const float* __restrict__ c_in,
    const __hip_bfloat16* __restrict__ Axh,
    const __hip_bfloat16* __restrict__ Wt,
    const float* __restrict__ bias_p,
    float* __restrict__ out) {
    __shared__ __hip_bfloat16 lds_a[128 * 32];   // 8KB, swizzled slots
    __shared__ __hip_bfloat16 lds_b[128 * 32];   // 8KB

    const int tid   = threadIdx.x;
    const int w     = tid >> 6;
    const int lane  = tid & 63;
    const int col16 = lane & 15;
    const int quad  = lane >> 4;

    // XCD-aware decomposition: assume round-robin block->XCD (j & 7).
    const int jb    = blockIdx.x;
    const int xcd   = jb & 7;
    const int local = jb >> 3;                   // 0..255 per XCD
    const int bm    = xcd * 16 + (local >> 4);   // 0..127
    const int bn    = local & 15;                // 0..15

    f32x4 acc[2][8];
#pragma unroll
    for (int mi = 0; mi < 2; ++mi)
#pragma unroll
        for (int ni = 0; ni < 8; ++ni)
            acc[mi][ni] = (f32x4){0.f, 0.f, 0.f, 0.f};

    const __hip_bfloat16* Ab = Axh + (size_t)bm * 128 * K_DIM;
    const __hip_bfloat16* Bb = Wt  + (size_t)bn * 128 * K_DIM;

    // Staging geometry: wave w fills chunks {2w, 2w+1} of each tile.
    // slot s holds row r = s>>2, k-group q = ((s&3) - ((r>>1)&3)) & 3.
    const int s0 = w * 128 + lane;
    const int s1 = s0 + 64;
    const int r0 = s0 >> 2, r1 = s1 >> 2;
    const int q0 = ((s0 & 3) - ((r0 >> 1) & 3)) & 3;
    const int q1 = ((s1 & 3) - ((r1 >> 1) & 3)) & 3;
    const size_t ga0 = (size_t)r0 * K_DIM + q0 * 8;
    const size_t ga1 = (size_t)r1 * K_DIM + q1 * 8;
    __hip_bfloat16* la0 = lds_a + w * 1024;
    __hip_bfloat16* la1 = lds_a + w * 1024 + 512;
    __hip_bfloat16* lb0 = lds_b + w * 1024;
    __hip_bfloat16* lb1 = lds_b + w * 1024 + 512;

    // ds_read byte offsets (constant across K loop)
    int aoff[2], boff[8];
#pragma unroll
    for (int mi = 0; mi < 2; ++mi) {
        int r = w * 32 + mi * 16 + col16;
        aoff[mi] = (r * 4 + ((quad + ((r >> 1) & 3)) & 3)) * 16;
    }
#pragma unroll
    for (int ni = 0; ni < 8; ++ni) {
        int r = ni * 16 + col16;
        boff[ni] = (r * 4 + ((quad + ((r >> 1) & 3)) & 3)) * 16;
    }
    const char* lap = (const char*)lds_a;
    const char* lbp = (const char*)lds_b;

    for (int kt = 0; kt < 32; ++kt) {
        const int kb = kt * 32;
        async_load16(Ab + ga0 + kb, la0);
        async_load16(Ab + ga1 + kb, la1);
        async_load16(Bb + ga0 + kb, lb0);
        async_load16(Bb + ga1 + kb, lb1);
        __syncthreads();

        short8 afr[2], bfr[8];
#pragma unroll
        for (int mi = 0; mi < 2; ++mi)
            afr[mi] = *(const short8*)(lap + aoff[mi]);
#pragma unroll
        for (int ni = 0; ni < 8; ++ni)
            bfr[ni] = *(const short8*)(lbp + boff[ni]);
#pragma unroll
        for (int mi = 0; mi < 2; ++mi)
#pragma unroll
            for (int ni = 0; ni < 8; ++ni)
                acc[mi][ni] = __builtin_amdgcn_mfma_f32_16x16x32_bf16(
                    afr[mi], bfr[ni], acc[mi][ni], 0, 0, 0);
        __syncthreads();
    }

    // ---- fused LSTM epilogue ----
    float bias_v[4][2];
#pragma unroll
    for (int g = 0; g < 4; ++g)
#pragma unroll
        for (int h2 = 0; h2 < 2; ++h2)
            bias_v[g][h2] = bias_p[bn * 128 + g * 32 + h2 * 16 + col16];

#pragma unroll
    for (int mi = 0; mi < 2; ++mi) {
#pragma unroll
        for (int reg = 0; reg < 4; ++reg) {
            const int m_g = bm * 128 + w * 32 + mi * 16 + quad * 4 + reg;
#pragma unroll
            for (int h2 = 0; h2 < 2; ++h2) {
                const int hc_g = bn * 32 + h2 * 16 + col16;
                float gi = acc[mi][0 + h2][reg] + bias_v[0][h2];
                float gf = acc[mi][2 + h2][reg] + bias_v[1][h2];
                float gg = acc[mi][4 + h2][reg] + bias_v[2][h2];
                float go = acc[mi][6 + h2][reg] + bias_v[3][h2];
                float iv = sigmoidf_(gi);
                float fv = sigmoidf_(gf);
                float gv = tanhf_(gg);
                float ov = sigmoidf_(go);
                float co = c_in[(size_t)m_g * H_DIM + hc_g];
                float cn = fv * co + iv * gv;
                float hn = ov * tanhf_(cn);
                out[(size_t)m_g * H_DIM + hc_g]      = hn;   // h_new
                out[BH + (size_t)m_g * H_DIM + hc_g] = cn;   // c_new
            }
        }
    }
}

// ---------------------------------------------------------------------------
// Fallback path (validated R1 kernels) in case ws_size < 36 MB.
// ---------------------------------------------------------------------------
__global__ __launch_bounds__(256) void prep_weights_fb(
    const float* __restrict__ Wx, const float* __restrict__ Wh,
    const float* __restrict__ bx, const float* __restrict__ bh,
    __hip_bfloat16* __restrict__ Wt, float* __restrict__ bias_p) {
    __shared__ __hip_bfloat16 tile[32][33];
    const int bid = blockIdx.x;
    const int bk  = bid & 31;
    const int bn  = bid >> 5;
    const int t   = threadIdx.x;
    const int kb  = bk * 32, nb = bn * 32;
#pragma unroll
    for (int r = 0; r < 4; ++r) {
        int k_loc = r * 8 + (t >> 5);
        int n_loc = t & 31;
        int kg = kb + k_loc;
        float v = (kg < IN_DIM) ? Wx[(size_t)kg * N4H + nb + n_loc]
                                : Wh[(size_t)(kg - IN_DIM) * N4H + nb + n_loc];
        tile[k_loc][n_loc] = __float2bfloat16(v);
    }
    __syncthreads();
    {
        int n_loc = t >> 3;
        int k_loc = (t & 7) * 4;
        int ng = nb + n_loc;
        int g  = ng >> 9;
        int c  = ng & 511;
        int row_out = (c >> 5) * 128 + g * 32 + (c & 31);
        short4v v4;
        v4.x = *reinterpret_cast<short*>(&tile[k_loc + 0][n_loc]);
        v4.y = *reinterpret_cast<short*>(&tile[k_loc + 1][n_loc]);
        v4.z = *reinterpret_cast<short*>(&tile[k_loc + 2][n_loc]);
        v4.w = *reinterpret_cast<short*>(&tile[k_loc + 3][n_loc]);
        *(short4v*)&Wt[(size_t)row_out * K_DIM + kb + k_loc] = v4;
    }
    if (bid < 8) {
        int ng = bid * 256 + t;
        int g  = ng >> 9;
        int c  = ng & 511;
        int ro = (c >> 5) * 128 + g * 32 + (c & 31);
        bias_p[ro] = bx[ng] + bh[ng];
    }
}

__global__ __launch_bounds__(256, 3) void lstm_gemm_fb(
    const float* __restrict__ x, const float* __restrict__ h,
    const float* __restrict__ c_in,
    const __hip_bfloat16* __restrict__ Wt, const float* __restrict__ bias_p,
    float* __restrict__ out) {
    __shared__ __hip_bfloat16 lds_a[128 * 32];
    __shared__ __hip_bfloat16 lds_b[128 * 32];
    const int tid   = threadIdx.x;
    const int bn    = blockIdx.x & 15;
    const int bm    = blockIdx.x >> 4;
    const int w     = tid >> 6;
    const int lane  = tid & 63;
    const int col16 = lane & 15;
    const int quad  = lane >> 4;
    f32x4 acc[2][8];
#pragma unroll
    for (int mi = 0; mi < 2; ++mi)
#pragma unroll
        for (int ni = 0; ni < 8; ++ni)
            acc[mi][ni] = (f32x4){0.f, 0.f, 0.f, 0.f};
    const __hip_bfloat16* wt_base = Wt + (size_t)(bn * 128) * K_DIM;
    const int chunk0 = w * 2;
    const int e0     = chunk0 * 512 + lane * 8;
    const int bn_loc0 = e0 >> 5, bk_off0 = e0 & 31;
    const int e1     = (chunk0 + 1) * 512 + lane * 8;
    const int bn_loc1 = e1 >> 5, bk_off1 = e1 & 31;
    for (int kt = 0; kt < 32; ++kt) {
        const int kb = kt * 32;
        const float* aptr;
        int koff;
        if (kb < IN_DIM) { aptr = x; koff = kb; }
        else             { aptr = h; koff = kb - IN_DIM; }
        async_load16(wt_base + (size_t)bn_loc0 * K_DIM + kb + bk_off0,
                     (void*)(lds_b + chunk0 * 512));
        async_load16(wt_base + (size_t)bn_loc1 * K_DIM + kb + bk_off1,
                     (void*)(lds_b + (chunk0 + 1) * 512));
        float4 av[4];
#pragma unroll
        for (int j = 0; j < 4; ++j) {
            int cch = j * 256 + tid;
            int row = cch >> 3;
            int kq  = (cch & 7) * 4;
            av[j] = *(const float4*)(aptr + (size_t)(bm * 128 + row) * IN_DIM
                                     + koff + kq);
        }
#pragma unroll
        for (int j = 0; j < 4; ++j) {
            int cch = j * 256 + tid;
            int row = cch >> 3;
            int kq  = (cch & 7) * 4;
            short4v sv;
            sv.x = bf16bits(av[j].x);
            sv.y = bf16bits(av[j].y);
            sv.z = bf16bits(av[j].z);
            sv.w = bf16bits(av[j].w);
            *(short4v*)&lds_a[row * 32 + kq] = sv;
        }
        __syncthreads();
        short8 afr[2], bfr[8];
#pragma unroll
        for (int mi = 0; mi < 2; ++mi)
            afr[mi] = *(const short8*)&lds_a[(w * 32 + mi * 16 + col16) * 32 + quad * 8];
#pragma unroll
        for (int ni = 0; ni < 8; ++ni)
            bfr[ni] = *(const short8*)&lds_b[(ni * 16 + col16) * 32 + quad * 8];
#pragma unroll
        for (int mi = 0; mi < 2; ++mi)
#pragma unroll
            for (int ni = 0; ni < 8; ++ni)
                acc[mi][ni] = __builtin_amdgcn_mfma_f32_16x16x32_bf16(
                    afr[mi], bfr[ni], acc[mi][ni], 0, 0, 0);
        __syncthreads();
    }
    float bias_v[4][2];
#pragma unroll
    for (int g = 0; g < 4; ++g)
#pragma unroll
        for (int h2 = 0; h2 < 2; ++h2)
            bias_v[g][h2] = bias_p[bn * 128 + g * 32 + h2 * 16 + col16];
#pragma unroll
    for (int mi = 0; mi < 2; ++mi) {
#pragma unroll
        for (int reg = 0; reg < 4; ++reg) {
            const int m_g = bm * 128 + w * 32 + mi * 16 + quad * 4 + reg;
#pragma unroll
            for (int h2 = 0; h2 < 2; ++h2) {
                const int hc_g = bn * 32 + h2 * 16 + col16;
                float gi = acc[mi][0 + h2][reg] + bias_v[0][h2];
                float gf = acc[mi][2 + h2][reg] + bias_v[1][h2];
                float gg = acc[mi][4 + h2][reg] + bias_v[2][h2];
                float go = acc[mi][6 + h2][reg] + bias_v[3][h2];
                float iv = sigmoidf_(gi);
                float fv = sigmoidf_(gf);
                float gv = tanhf_(gg);
                float ov = sigmoidf_(go);
                float co = c_in[(size_t)m_g * H_DIM + hc_g];
                float cn = fv * co + iv * gv;
                float hn = ov * tanhf_(cn);
                out[(size_t)m_g * H_DIM + hc_g]      = hn;
                out[BH + (size_t)m_g * H_DIM + hc_g] = cn;
            }
        }
    }
}

extern "C" void kernel_launch(void* const* d_in, const int* in_sizes, int n_in,
                              void* d_out, int out_size, void* d_ws, size_t ws_size,
                              hipStream_t stream) {
    const float* x  = (const float*)d_in[0];
    const float* h  = (const float*)d_in[1];
    const float* c  = (const float*)d_in[2];
    const float* Wx = (const float*)d_in[3];
    const float* Wh = (const float*)d_in[4];
    const float* bx = (const float*)d_in[5];
    const float* bh = (const float*)d_in[6];

    const size_t wtBytes  = (size_t)N4H * K_DIM * 2;    // 4 MB
    const size_t axhBytes = (size_t)B_DIM * K_DIM * 2;  // 32 MB
    const size_t need     = wtBytes + axhBytes + (size_t)N4H * 4;

    if (ws_size >= need) {
        __hip_bfloat16* Wt  = (__hip_bfloat16*)d_ws;
        __hip_bfloat16* Axh = (__hip_bfloat16*)((char*)d_ws + wtBytes);
        float* bias_p = (float*)((char*)d_ws + wtBytes + axhBytes);
        prep_all<<<4096, 256, 0, stream>>>(Wx, Wh, bx, bh, x, h, Wt, Axh, bias_p);
        lstm_gemm<<<2048, 256, 0, stream>>>(c, Axh, Wt, bias_p, (float*)d_out);
    } else {
        __hip_bfloat16* Wt = (__hip_bfloat16*)d_ws;
        float* bias_p = (float*)((char*)d_ws + wtBytes);
        prep_weights_fb<<<2048, 256, 0, stream>>>(Wx, Wh, bx, bh, Wt, bias_p);
        lstm_gemm_fb<<<2048, 256, 0, stream>>>(x, h, c, Wt, bias_p, (float*)d_out);
    }
}